// Round 12
// baseline (121.955 us; speedup 1.0000x reference)
//
#include <hip/hip_runtime.h>

#define BB 4
#define NN 4096
#define CC 128
#define NROWS (BB * NN)   // 16384 rows per tensor

// workspace layout (float offsets)
#define QN_OFF  0                              // |q_proj| per row (16384)
#define QP_OFF  (QN_OFF + NROWS)               // projected q, 16384 x 128
#define MM_OFF  (QP_OFF + NROWS * CC)          // B x 128 x 128  M = M0 W^T + Ksum b^T
#define KS_OFF  (MM_OFF + BB * CC * CC)        // B x 128  Ksum (sum of khat rows)
#define PP_OFF  (KS_OFF + BB * CC)             // 256 x 16384 partial M0s
#define KP_OFF  (PP_OFF + 256 * CC * CC)       // 256 x 128 partial ksums

typedef __attribute__((ext_vector_type(8))) short short8;
typedef __attribute__((ext_vector_type(4))) float f32x4;

__device__ __forceinline__ float dot4(const float4 x, const float4 k)
{
    return x.x * k.x + x.y * k.y + x.z * k.z + x.w * k.w;
}

__device__ __forceinline__ unsigned short f2bf(float f)
{
    union { float f; unsigned u; } v; v.f = f;
    unsigned r = (v.u + 0x7fffu + ((v.u >> 16) & 1u)) >> 16;   // RNE
    return (unsigned short)r;
}
__device__ __forceinline__ float bf2f(unsigned short h)
{
    union { unsigned u; float f; } v; v.u = ((unsigned)h) << 16;
    return v.f;
}

// ---------------------------------------------------------------------------
// Kernel 1 (R11, validated): fused projection (3-way-split bf16 MFMA) +
// partial-M build (fp32 VALU). 256 blocks x 512 threads (8 waves).
// ---------------------------------------------------------------------------
__global__ __launch_bounds__(512, 1) void projpb_kernel(
    const float* __restrict__ q_node, const float* __restrict__ k_node,
    const float* __restrict__ v_node, const float* __restrict__ W,
    const float* __restrict__ bias, float* __restrict__ ws)
{
    __shared__ __align__(16) unsigned short Wsp[3 * CC * CC];  // 96 KB
    __shared__ float4 red[512];                                 // 8 KB
    unsigned short* Whi = Wsp;                 // [col][swizzled k] 128x128
    unsigned short* Wmd = Wsp + CC * CC;
    unsigned short* Wlo = Wsp + 2 * CC * CC;

    const int tid = threadIdx.x;

    // stage W as 3-way split bf16. B[k][c] = W[colbase+c][k] (out = X W^T).
    for (int e = tid; e < CC * CC; e += 512) {
        int col = e >> 7, k = e & 127;
        float wv = W[e];
        unsigned short hi = f2bf(wv);
        float r1 = wv - bf2f(hi);
        unsigned short md = f2bf(r1);
        unsigned short lo = f2bf(r1 - bf2f(md));
        int idx = (col << 7) + ((((k >> 3) ^ (col & 7)) << 3) | (k & 7));
        Whi[idx] = hi; Wmd[idx] = md; Wlo[idx] = lo;
    }

    const int blk  = blockIdx.x;      // 0..255
    const int base = blk * 64;
    const int w    = tid >> 6;        // wave 0..7
    const int lane = tid & 63;
    const int l15  = lane & 15;       // A-row / B-col / C-col within tile
    const int lg   = lane >> 4;       // k-group 0..3
    const bool isq = (w < 4);
    const int rt   = w & 3;           // row-tile within its tensor
    const float* X = isq ? q_node : k_node;
    const int arow = base + rt * 16 + l15;   // this lane's A row (global)

    f32x4 acc[8];
#pragma unroll
    for (int ct = 0; ct < 8; ct++) {
        float b = bias[ct * 16 + l15];
        acc[ct] = (f32x4){b, b, b, b};
    }

    __syncthreads();   // W staged

    const float* Xr = X + (size_t)arow * CC;
#pragma unroll
    for (int ks = 0; ks < 4; ks++) {
        const int k0 = ks * 32 + lg * 8;
        float4 xa = *(const float4*)(Xr + k0);
        float4 xb = *(const float4*)(Xr + k0 + 4);
        float xs[8] = {xa.x, xa.y, xa.z, xa.w, xb.x, xb.y, xb.z, xb.w};
        short8 Ahi, Amd, Alo;
#pragma unroll
        for (int j = 0; j < 8; j++) {
            unsigned short h = f2bf(xs[j]);
            float r1 = xs[j] - bf2f(h);
            unsigned short m = f2bf(r1);
            Ahi[j] = (short)h;
            Amd[j] = (short)m;
            Alo[j] = (short)f2bf(r1 - bf2f(m));
        }
        const int slot = ks * 4 + lg;      // k0 >> 3
#pragma unroll
        for (int ct = 0; ct < 8; ct++) {
            int col  = ct * 16 + l15;
            int fidx = (col << 7) + ((slot ^ (col & 7)) << 3);
            short8 Bhi = *(const short8*)(Whi + fidx);
            short8 Bmd = *(const short8*)(Wmd + fidx);
            short8 Blo = *(const short8*)(Wlo + fidx);
            acc[ct] = __builtin_amdgcn_mfma_f32_16x16x32_bf16(Ahi, Bhi, acc[ct], 0, 0, 0);
            acc[ct] = __builtin_amdgcn_mfma_f32_16x16x32_bf16(Ahi, Bmd, acc[ct], 0, 0, 0);
            acc[ct] = __builtin_amdgcn_mfma_f32_16x16x32_bf16(Amd, Bhi, acc[ct], 0, 0, 0);
            acc[ct] = __builtin_amdgcn_mfma_f32_16x16x32_bf16(Ahi, Blo, acc[ct], 0, 0, 0);
            acc[ct] = __builtin_amdgcn_mfma_f32_16x16x32_bf16(Amd, Bmd, acc[ct], 0, 0, 0);
            acc[ct] = __builtin_amdgcn_mfma_f32_16x16x32_bf16(Alo, Bhi, acc[ct], 0, 0, 0);
        }
    }

    // C/D layout (HW-verified): col = lane&15, row = (lane>>4)*4 + reg.
    float ss[4];
#pragma unroll
    for (int r = 0; r < 4; r++) {
        float t = 0.f;
#pragma unroll
        for (int ct = 0; ct < 8; ct++) t += acc[ct][r] * acc[ct][r];
#pragma unroll
        for (int off = 8; off > 0; off >>= 1) t += __shfl_xor(t, off, 16);
        ss[r] = t;
    }

    if (isq) {
#pragma unroll
        for (int r = 0; r < 4; r++) {
            int gr = base + rt * 16 + lg * 4 + r;
            float* qp = ws + QP_OFF + (size_t)gr * CC;
#pragma unroll
            for (int ct = 0; ct < 8; ct++) qp[ct * 16 + l15] = acc[ct][r];
            if (l15 == 0) ws[QN_OFF + gr] = sqrtf(ss[r]);
        }
    }

    __syncthreads();   // all waves done reading W LDS before overwrite

    float* Khs = (float*)Wsp;          // 64 x 128 f32 (32 KB)
    float* Vs  = Khs + 8192;           // 64 x 128 f32 (32 KB)

    if (!isq) {
#pragma unroll
        for (int r = 0; r < 4; r++) {
            float inv = 1.0f / sqrtf(ss[r]);
            int lr = rt * 16 + lg * 4 + r;       // local k row 0..63
            float* kp = Khs + lr * CC;
#pragma unroll
            for (int ct = 0; ct < 8; ct++) kp[ct * 16 + l15] = acc[ct][r] * inv;
        }
    }

    // stage v rows 64x128 (each thread 4 float4)
    const int c4v = tid & 31, nrv = tid >> 5;   // nrv 0..15
    const float* Vp = v_node + (size_t)base * CC;
#pragma unroll
    for (int i = 0; i < 4; i++) {
        int n = nrv + i * 16;
        ((float4*)(Vs + n * CC))[c4v] = ((const float4*)(Vp + (size_t)n * CC))[c4v];
    }
    __syncthreads();

    // partial ksum (column sums of khat)
    float4 ksum4 = make_float4(0.f, 0.f, 0.f, 0.f);
#pragma unroll
    for (int i = 0; i < 4; i++) {
        int n = nrv + i * 16;
        float4 kv = ((const float4*)(Khs + n * CC))[c4v];
        ksum4.x += kv.x; ksum4.y += kv.y; ksum4.z += kv.z; ksum4.w += kv.w;
    }

    // rank-64 outer product, software-pipelined over n (validated R5/R9)
    const int dg2 = tid & 15, cg = tid >> 4;    // cg 0..31
    float a2[4][8];
#pragma unroll
    for (int i = 0; i < 4; i++)
#pragma unroll
        for (int j = 0; j < 8; j++) a2[i][j] = 0.f;

#define P2L(ka, va, vb, n)                                  \
    ka = *(const float4*)(Khs + (n) * CC + 4 * cg);         \
    va = *(const float4*)(Vs + (n) * CC + 4 * dg2);         \
    vb = *(const float4*)(Vs + (n) * CC + 64 + 4 * dg2);
#define P2F(ka, va, vb)                                     \
    {  float kc[4] = {ka.x, ka.y, ka.z, ka.w};              \
       float vd[8] = {va.x, va.y, va.z, va.w,               \
                      vb.x, vb.y, vb.z, vb.w};              \
       _Pragma("unroll")                                    \
       for (int i = 0; i < 4; i++)                          \
           { _Pragma("unroll")                              \
             for (int j = 0; j < 8; j++)                    \
                 a2[i][j] += kc[i] * vd[j]; } }

    {
        float4 kaA, vaA, vbA, kaB, vaB, vbB;
        P2L(kaA, vaA, vbA, 0)
        for (int n = 0; n <= 60; n += 2) {
            P2L(kaB, vaB, vbB, n + 1)
            P2F(kaA, vaA, vbA)
            P2L(kaA, vaA, vbA, n + 2)
            P2F(kaB, vaB, vbB)
        }
        P2L(kaB, vaB, vbB, 63)
        P2F(kaA, vaA, vbA)
        P2F(kaB, vaB, vbB)
    }
#undef P2L
#undef P2F

    float* pp = ws + PP_OFF + (size_t)blk * (CC * CC);
#pragma unroll
    for (int i = 0; i < 4; i++) {
        int c = 4 * cg + i;
        *(float4*)(pp + c * CC + 4 * dg2) =
            make_float4(a2[i][0], a2[i][1], a2[i][2], a2[i][3]);
        *(float4*)(pp + c * CC + 64 + 4 * dg2) =
            make_float4(a2[i][4], a2[i][5], a2[i][6], a2[i][7]);
    }

    red[nrv * 32 + c4v] = ksum4;
    __syncthreads();
    if (tid < 32) {
        float4 sm = red[tid];
#pragma unroll
        for (int i = 1; i < 16; i++) {
            float4 t = red[i * 32 + tid];
            sm.x += t.x; sm.y += t.y; sm.z += t.z; sm.w += t.w;
        }
        ((float4*)(ws + KP_OFF + (size_t)blk * CC))[tid] = sm;
    }
}

// ---------------------------------------------------------------------------
// Kernel 2 (R9, validated): fused reduce + M-build, float4-vectorized.
// ---------------------------------------------------------------------------
__global__ __launch_bounds__(256) void mchain_kernel(const float* __restrict__ W,
                                                     const float* __restrict__ bias,
                                                     float* __restrict__ ws)
{
    __shared__ float4 W4s[CC * 32];    // W natural, float4-swizzled per row (64 KB)
    __shared__ float4 m0q[4][2][32];   // quarter partial sums (4 KB)
    __shared__ float m0row[2][CC];
    __shared__ float kpart[4];
    __shared__ float ksl[2];
    const int tid = threadIdx.x;
    const int b = blockIdx.y, x = blockIdx.x;
    const int c0 = x * 2;

    for (int idx = tid; idx < CC * 32; idx += 256) {
        int e = idx >> 5, d4 = idx & 31;
        W4s[(e << 5) + (d4 ^ (e & 31))] = ((const float4*)W)[idx];
    }

    // reduce 2 rows of M0 over 64 partials: 4-way quarter split, float4 loads
    {
        const int q  = tid >> 6;           // 0..3 partial quarter
        const int r  = (tid >> 5) & 1;     // row within pair
        const int c4 = tid & 31;           // float4 column
        const float4* pp = (const float4*)(ws + PP_OFF
                         + (size_t)(b * 64 + q * 16) * (CC * CC)
                         + (size_t)(c0 + r) * CC) + c4;
        float4 s0 = make_float4(0.f, 0.f, 0.f, 0.f);
#pragma unroll 4
        for (int p = 0; p < 16; p++) {
            float4 t = pp[(size_t)p * (CC * CC / 4)];
            s0.x += t.x; s0.y += t.y; s0.z += t.z; s0.w += t.w;
        }
        m0q[q][r][c4] = s0;
    }

    // reduce 2 Ksum entries over 64 partials
    {
        const int rr = tid >> 7, p = tid & 127;
        float v = 0.f;
        if (p < 64) v = ws[KP_OFF + (size_t)(b * 64 + p) * CC + c0 + rr];
#pragma unroll
        for (int off = 32; off > 0; off >>= 1) v += __shfl_xor(v, off, 64);
        if ((tid & 63) == 0) kpart[tid >> 6] = v;
    }
    __syncthreads();

    if (tid < 64) {
        const int r = tid >> 5, c4 = tid & 31;
        float4 a = m0q[0][r][c4], bq = m0q[1][r][c4];
        float4 c = m0q[2][r][c4], d = m0q[3][r][c4];
        float4 s;
        s.x = (a.x + bq.x) + (c.x + d.x);
        s.y = (a.y + bq.y) + (c.y + d.y);
        s.z = (a.z + bq.z) + (c.z + d.z);
        s.w = (a.w + bq.w) + (c.w + d.w);
        ((float4*)&m0row[r][0])[c4] = s;
    }
    if (tid < 2) {
        float s = kpart[tid * 2] + kpart[tid * 2 + 1];
        ksl[tid] = s;
        ws[KS_OFF + b * CC + c0 + tid] = s;
    }
    __syncthreads();

    // M = M0 @ W^T + Ksum b^T  (thread -> one output element)
    const int r = tid >> 7, e = tid & 127;
    const float4* mr = (const float4*)m0row[r];
    float m = 0.f;
#pragma unroll
    for (int d4 = 0; d4 < 32; d4++) {
        float4 a4 = mr[d4];                              // broadcast
        float4 w4 = W4s[(e << 5) + (d4 ^ (e & 31))];     // conflict-spread
        m += a4.x * w4.x + a4.y * w4.y + a4.z * w4.z + a4.w * w4.w;
    }
    m += ksl[r] * bias[e];
    ws[MM_OFF + (size_t)b * CC * CC + (size_t)(c0 + r) * CC + e] = m;
}

// ---------------------------------------------------------------------------
// Kernel 3: out[b,r,:] = (q_proj[r] @ M) / (q_proj[r].Ksum + 1e-8*|q_proj[r]|)
// NEW: 6-term split-bf16 MFMA numerator (template from validated projpb);
// denominator s = q.Ksum stays exact fp32 VALU. 256 blocks x 512 threads
// (8 waves = 4 row-tiles x 2 col-halves), 64 rows/block, 96 KB LDS.
// M is naturally [k=c][col=e] -> B-operand orientation directly.
// ---------------------------------------------------------------------------
__global__ __launch_bounds__(512, 1) void out_kernel(const float* __restrict__ ws,
                                                     float* __restrict__ out)
{
    __shared__ __align__(16) unsigned short Msp[3 * CC * CC];  // 96 KB
    __shared__ float Ksl[CC];
    unsigned short* Mhi = Msp;
    unsigned short* Mmd = Msp + CC * CC;
    unsigned short* Mlo = Msp + 2 * CC * CC;

    const int tid = threadIdx.x;
    const int blk = blockIdx.x;     // 0..255
    const int b  = blk >> 6;
    const int r0 = (blk & 63) * 64;
    const float* M = ws + MM_OFF + (size_t)b * CC * CC;

    // stage M split-bf16: B[k][c] = M[k][colbase+c]; fragment plane layout
    // [col][swizzled k], slot = (k>>3) ^ (col&7).
    for (int e = tid; e < CC * CC; e += 512) {
        int k = e >> 7, col = e & 127;
        float mv = M[e];
        unsigned short hi = f2bf(mv);
        float r1 = mv - bf2f(hi);
        unsigned short md = f2bf(r1);
        unsigned short lo = f2bf(r1 - bf2f(md));
        int idx = (col << 7) + ((((k >> 3) ^ (col & 7)) << 3) | (k & 7));
        Mhi[idx] = hi; Mmd[idx] = md; Mlo[idx] = lo;
    }
    if (tid < CC) Ksl[tid] = ws[KS_OFF + b * CC + tid];

    const int w    = tid >> 6;        // wave 0..7
    const int lane = tid & 63;
    const int l15  = lane & 15;
    const int lg   = lane >> 4;
    const int rt   = w & 3;           // row-tile (4 x 16 = 64 rows)
    const int ch   = w >> 2;          // col-half (0: cols 0-63, 1: 64-127)

    const int arow = r0 + rt * 16 + l15;
    const float* Xr = ws + QP_OFF + ((size_t)b * NN + arow) * CC;

    f32x4 acc[4];
#pragma unroll
    for (int ct = 0; ct < 4; ct++) acc[ct] = (f32x4){0.f, 0.f, 0.f, 0.f};
    float sp = 0.f;

    __syncthreads();   // M + Ksum staged

#pragma unroll
    for (int ks = 0; ks < 4; ks++) {
        const int k0 = ks * 32 + lg * 8;
        float4 xa = *(const float4*)(Xr + k0);
        float4 xb = *(const float4*)(Xr + k0 + 4);
        float xs[8] = {xa.x, xa.y, xa.z, xa.w, xb.x, xb.y, xb.z, xb.w};
        short8 Ahi, Amd, Alo;
#pragma unroll
        for (int j = 0; j < 8; j++) {
            unsigned short h = f2bf(xs[j]);
            float r1 = xs[j] - bf2f(h);
            unsigned short m = f2bf(r1);
            Ahi[j] = (short)h;
            Amd[j] = (short)m;
            Alo[j] = (short)f2bf(r1 - bf2f(m));
            sp += xs[j] * Ksl[k0 + j];          // exact fp32 denominator
        }
        const int slot = ks * 4 + lg;
#pragma unroll
        for (int ct = 0; ct < 4; ct++) {
            int col  = ch * 64 + ct * 16 + l15;
            int fidx = (col << 7) + ((slot ^ (col & 7)) << 3);
            short8 Bhi = *(const short8*)(Mhi + fidx);
            short8 Bmd = *(const short8*)(Mmd + fidx);
            short8 Blo = *(const short8*)(Mlo + fidx);
            acc[ct] = __builtin_amdgcn_mfma_f32_16x16x32_bf16(Ahi, Bhi, acc[ct], 0, 0, 0);
            acc[ct] = __builtin_amdgcn_mfma_f32_16x16x32_bf16(Ahi, Bmd, acc[ct], 0, 0, 0);
            acc[ct] = __builtin_amdgcn_mfma_f32_16x16x32_bf16(Amd, Bhi, acc[ct], 0, 0, 0);
            acc[ct] = __builtin_amdgcn_mfma_f32_16x16x32_bf16(Ahi, Blo, acc[ct], 0, 0, 0);
            acc[ct] = __builtin_amdgcn_mfma_f32_16x16x32_bf16(Amd, Bmd, acc[ct], 0, 0, 0);
            acc[ct] = __builtin_amdgcn_mfma_f32_16x16x32_bf16(Alo, Bhi, acc[ct], 0, 0, 0);
        }
    }

    // reduce denominator over the 4 k-group lanes sharing l15
    sp += __shfl_xor(sp, 16, 64);
    sp += __shfl_xor(sp, 32, 64);
    // now every lane with a given l15 holds s for row (rt*16 + l15)

    // C/D layout: col = lane&15, row = lg*4 + r. Fetch s for the C-row.
#pragma unroll
    for (int r = 0; r < 4; r++) {
        const int rowt = lg * 4 + r;                 // row within 16-tile
        float srow = __shfl(sp, rowt, 64);           // lanes 0..15 hold rows 0..15
        const int gr = r0 + rt * 16 + rowt;
        float qn = ws[QN_OFF + (size_t)b * NN + gr];
        float inv = 1.0f / (srow + 1e-8f * qn);
        float* op = out + ((size_t)b * NN + gr) * CC + ch * 64;
#pragma unroll
        for (int ct = 0; ct < 4; ct++)
            op[ct * 16 + l15] = acc[ct][r] * inv;
    }
}

// ---------------------------------------------------------------------------
extern "C" void kernel_launch(void* const* d_in, const int* in_sizes, int n_in,
                              void* d_out, int out_size, void* d_ws, size_t ws_size,
                              hipStream_t stream)
{
    const float* q_node = (const float*)d_in[0];
    const float* k_node = (const float*)d_in[1];
    const float* v_node = (const float*)d_in[2];
    const float* W      = (const float*)d_in[3];
    const float* bias   = (const float*)d_in[4];
    float* out = (float*)d_out;
    float* ws  = (float*)d_ws;

    projpb_kernel<<<256, 512, 0, stream>>>(q_node, k_node, v_node, W, bias, ws);
    mchain_kernel<<<dim3(64, BB), 256, 0, stream>>>(W, bias, ws);
    out_kernel<<<256, 512, 0, stream>>>(ws, out);
}

// Round 13
// 121.557 us; speedup vs baseline: 1.0033x; 1.0033x over previous
//
#include <hip/hip_runtime.h>

#define BB 4
#define NN 4096
#define CC 128
#define NROWS (BB * NN)   // 16384 rows per tensor

// workspace layout (float offsets)
#define QN_OFF  0                              // |q_proj| per row (16384)
#define QP_OFF  (QN_OFF + NROWS)               // projected q, 16384 x 128
#define MM_OFF  (QP_OFF + NROWS * CC)          // B x 128 x 128  M = M0 W^T + Ksum b^T
#define KS_OFF  (MM_OFF + BB * CC * CC)        // B x 128  Ksum (sum of khat rows)
#define PP_OFF  (KS_OFF + BB * CC)             // 256 x 16384 partial M0s
#define KP_OFF  (PP_OFF + 256 * CC * CC)       // 256 x 128 partial ksums

typedef __attribute__((ext_vector_type(8))) short short8;
typedef __attribute__((ext_vector_type(4))) float f32x4;

__device__ __forceinline__ unsigned short f2bf(float f)
{
    union { float f; unsigned u; } v; v.f = f;
    unsigned r = (v.u + 0x7fffu + ((v.u >> 16) & 1u)) >> 16;   // RNE
    return (unsigned short)r;
}
__device__ __forceinline__ float bf2f(unsigned short h)
{
    union { unsigned u; float f; } v; v.u = ((unsigned)h) << 16;
    return v.f;
}

// ---------------------------------------------------------------------------
// Kernel 1: fused projection (3-way-split bf16 MFMA, validated R11) +
// partial-M build (NEW: also 6-term split-bf16 MFMA).
// 256 blocks x 512 threads (8 waves). Phase 1: waves 0-3 project 64 q rows,
// waves 4-7 project 64 k rows (W staged as 3 bf16 planes). Phase 2: khat
// staged transposed as 3 A-planes [c][swz n] from registers, v as 3 B-planes
// [d][swz n]; each wave computes a 16-c x 128-d tile of the rank-64 partial
// M0 with 96 MFMAs (was 192 ds_read_b128 + 2048 fp32 FMA per wave).
// ksum stays exact fp32 (register reduce). LDS: 96 KB planes + 2 KB red.
// ---------------------------------------------------------------------------
__global__ __launch_bounds__(512, 1) void projpb_kernel(
    const float* __restrict__ q_node, const float* __restrict__ k_node,
    const float* __restrict__ v_node, const float* __restrict__ W,
    const float* __restrict__ bias, float* __restrict__ ws)
{
    __shared__ __align__(16) unsigned short Wsp[3 * CC * CC];  // 96 KB
    __shared__ float redf[512];                                 // 2 KB
    unsigned short* Whi = Wsp;                 // [col][swizzled k] 128x128
    unsigned short* Wmd = Wsp + CC * CC;
    unsigned short* Wlo = Wsp + 2 * CC * CC;

    const int tid = threadIdx.x;

    // stage W as 3-way split bf16. B[k][c] = W[colbase+c][k] (out = X W^T).
    for (int e = tid; e < CC * CC; e += 512) {
        int col = e >> 7, k = e & 127;
        float wv = W[e];
        unsigned short hi = f2bf(wv);
        float r1 = wv - bf2f(hi);
        unsigned short md = f2bf(r1);
        unsigned short lo = f2bf(r1 - bf2f(md));
        int idx = (col << 7) + ((((k >> 3) ^ (col & 7)) << 3) | (k & 7));
        Whi[idx] = hi; Wmd[idx] = md; Wlo[idx] = lo;
    }

    const int blk  = blockIdx.x;      // 0..255
    const int base = blk * 64;
    const int w    = tid >> 6;        // wave 0..7
    const int lane = tid & 63;
    const int l15  = lane & 15;       // A-row / B-col / C-col within tile
    const int lg   = lane >> 4;       // k-group 0..3
    const bool isq = (w < 4);
    const int rt   = w & 3;           // row-tile within its tensor
    const float* X = isq ? q_node : k_node;
    const int arow = base + rt * 16 + l15;   // this lane's A row (global)

    f32x4 acc[8];
#pragma unroll
    for (int ct = 0; ct < 8; ct++) {
        float b = bias[ct * 16 + l15];
        acc[ct] = (f32x4){b, b, b, b};
    }

    __syncthreads();   // W staged

    const float* Xr = X + (size_t)arow * CC;
#pragma unroll
    for (int ks = 0; ks < 4; ks++) {
        const int k0 = ks * 32 + lg * 8;
        float4 xa = *(const float4*)(Xr + k0);
        float4 xb = *(const float4*)(Xr + k0 + 4);
        float xs[8] = {xa.x, xa.y, xa.z, xa.w, xb.x, xb.y, xb.z, xb.w};
        short8 Ahi, Amd, Alo;
#pragma unroll
        for (int j = 0; j < 8; j++) {
            unsigned short h = f2bf(xs[j]);
            float r1 = xs[j] - bf2f(h);
            unsigned short m = f2bf(r1);
            Ahi[j] = (short)h;
            Amd[j] = (short)m;
            Alo[j] = (short)f2bf(r1 - bf2f(m));
        }
        const int slot = ks * 4 + lg;      // k0 >> 3
#pragma unroll
        for (int ct = 0; ct < 8; ct++) {
            int col  = ct * 16 + l15;
            int fidx = (col << 7) + ((slot ^ (col & 7)) << 3);
            short8 Bhi = *(const short8*)(Whi + fidx);
            short8 Bmd = *(const short8*)(Wmd + fidx);
            short8 Blo = *(const short8*)(Wlo + fidx);
            acc[ct] = __builtin_amdgcn_mfma_f32_16x16x32_bf16(Ahi, Bhi, acc[ct], 0, 0, 0);
            acc[ct] = __builtin_amdgcn_mfma_f32_16x16x32_bf16(Ahi, Bmd, acc[ct], 0, 0, 0);
            acc[ct] = __builtin_amdgcn_mfma_f32_16x16x32_bf16(Amd, Bhi, acc[ct], 0, 0, 0);
            acc[ct] = __builtin_amdgcn_mfma_f32_16x16x32_bf16(Ahi, Blo, acc[ct], 0, 0, 0);
            acc[ct] = __builtin_amdgcn_mfma_f32_16x16x32_bf16(Amd, Bmd, acc[ct], 0, 0, 0);
            acc[ct] = __builtin_amdgcn_mfma_f32_16x16x32_bf16(Alo, Bhi, acc[ct], 0, 0, 0);
        }
    }

    // C/D layout (HW-verified): col = lane&15, row = (lane>>4)*4 + reg.
    float ss[4];
#pragma unroll
    for (int r = 0; r < 4; r++) {
        float t = 0.f;
#pragma unroll
        for (int ct = 0; ct < 8; ct++) t += acc[ct][r] * acc[ct][r];
#pragma unroll
        for (int off = 8; off > 0; off >>= 1) t += __shfl_xor(t, off, 16);
        ss[r] = t;
    }

    if (isq) {
#pragma unroll
        for (int r = 0; r < 4; r++) {
            int gr = base + rt * 16 + lg * 4 + r;
            float* qp = ws + QP_OFF + (size_t)gr * CC;
#pragma unroll
            for (int ct = 0; ct < 8; ct++) qp[ct * 16 + l15] = acc[ct][r];
            if (l15 == 0) ws[QN_OFF + gr] = sqrtf(ss[r]);
        }
    }

    __syncthreads();   // all waves done reading W LDS before overwrite

    // -------- phase 2: rank-64 partial M0 via split-bf16 MFMA --------
    // A-planes: khat^T [c=128][n=64 swz], B-planes: v [d=128][n=64 swz].
    unsigned short* Ahi_p = Wsp;               // 6 planes x 8192 shorts
    unsigned short* Amd_p = Wsp + 8192;
    unsigned short* Alo_p = Wsp + 16384;
    unsigned short* Bhi_p = Wsp + 24576;
    unsigned short* Bmd_p = Wsp + 32768;
    unsigned short* Blo_p = Wsp + 40960;

    // k-waves: normalize khat from registers -> A-planes + exact ksum partials
    if (!isq) {
        float ksp[8] = {0.f, 0.f, 0.f, 0.f, 0.f, 0.f, 0.f, 0.f};
#pragma unroll
        for (int r = 0; r < 4; r++) {
            float inv = 1.0f / sqrtf(ss[r]);
            int n = rt * 16 + lg * 4 + r;       // local n 0..63
#pragma unroll
            for (int ct = 0; ct < 8; ct++) {
                int c = ct * 16 + l15;
                float val = acc[ct][r] * inv;
                unsigned short h = f2bf(val);
                float r1 = val - bf2f(h);
                unsigned short m = f2bf(r1);
                unsigned short l = f2bf(r1 - bf2f(m));
                int idx = (c << 6) + ((((n >> 3) ^ (c & 7)) << 3) | (n & 7));
                Ahi_p[idx] = h; Amd_p[idx] = m; Alo_p[idx] = l;
                ksp[ct] += val;
            }
        }
#pragma unroll
        for (int ct = 0; ct < 8; ct++) {
            ksp[ct] += __shfl_xor(ksp[ct], 16, 64);
            ksp[ct] += __shfl_xor(ksp[ct], 32, 64);
            if (lg == 0) redf[(rt * 8 + ct) * 16 + l15] = ksp[ct];
        }
    }

    // all threads: stage v -> B-planes (scalar coalesced reads, d = c4v+32j
    // so b16 LDS writes spread across banks via the d&7 swizzle)
    {
        const int c4v = tid & 31, nrv = (tid >> 5) & 15;
        const float* Vp = v_node + (size_t)base * CC;
#pragma unroll
        for (int i = 0; i < 4; i++) {
            int n = nrv + i * 16;
#pragma unroll
            for (int j = 0; j < 4; j++) {
                int d = c4v + 32 * j;
                float val = Vp[(size_t)n * CC + d];
                unsigned short h = f2bf(val);
                float r1 = val - bf2f(h);
                unsigned short m = f2bf(r1);
                unsigned short l = f2bf(r1 - bf2f(m));
                int idx = (d << 6) + ((((n >> 3) ^ (d & 7)) << 3) | (n & 7));
                Bhi_p[idx] = h; Bmd_p[idx] = m; Blo_p[idx] = l;
            }
        }
    }
    __syncthreads();

    // MFMA: wave w -> c-tile w (16 c rows) x all 128 d, K = 64 (2 steps)
    {
        f32x4 macc[8];
#pragma unroll
        for (int dt = 0; dt < 8; dt++) macc[dt] = (f32x4){0.f, 0.f, 0.f, 0.f};
        const int crow = w * 16 + l15;
#pragma unroll
        for (int ks2 = 0; ks2 < 2; ks2++) {
            const int slot = ks2 * 4 + lg;
            int aidx = (crow << 6) + ((slot ^ (crow & 7)) << 3);
            short8 Ah = *(const short8*)(Ahi_p + aidx);
            short8 Am = *(const short8*)(Amd_p + aidx);
            short8 Al = *(const short8*)(Alo_p + aidx);
#pragma unroll
            for (int dt = 0; dt < 8; dt++) {
                int d = dt * 16 + l15;
                int bidx = (d << 6) + ((slot ^ (d & 7)) << 3);
                short8 Bh = *(const short8*)(Bhi_p + bidx);
                short8 Bm = *(const short8*)(Bmd_p + bidx);
                short8 Bl = *(const short8*)(Blo_p + bidx);
                macc[dt] = __builtin_amdgcn_mfma_f32_16x16x32_bf16(Ah, Bh, macc[dt], 0, 0, 0);
                macc[dt] = __builtin_amdgcn_mfma_f32_16x16x32_bf16(Ah, Bm, macc[dt], 0, 0, 0);
                macc[dt] = __builtin_amdgcn_mfma_f32_16x16x32_bf16(Am, Bh, macc[dt], 0, 0, 0);
                macc[dt] = __builtin_amdgcn_mfma_f32_16x16x32_bf16(Ah, Bl, macc[dt], 0, 0, 0);
                macc[dt] = __builtin_amdgcn_mfma_f32_16x16x32_bf16(Am, Bm, macc[dt], 0, 0, 0);
                macc[dt] = __builtin_amdgcn_mfma_f32_16x16x32_bf16(Al, Bh, macc[dt], 0, 0, 0);
            }
        }

        // write partial M0: c = w*16 + lg*4 + r, d = dt*16 + l15
        float* pp = ws + PP_OFF + (size_t)blk * (CC * CC);
#pragma unroll
        for (int dt = 0; dt < 8; dt++)
#pragma unroll
            for (int r = 0; r < 4; r++)
                pp[(size_t)(w * 16 + lg * 4 + r) * CC + dt * 16 + l15] = macc[dt][r];
    }

    // finalize ksum partial (exact fp32): lanes 0..15 of wave 0
    if (w == 0 && lg == 0) {
#pragma unroll
        for (int ct = 0; ct < 8; ct++) {
            float s = redf[(0 * 8 + ct) * 16 + l15] + redf[(1 * 8 + ct) * 16 + l15]
                    + redf[(2 * 8 + ct) * 16 + l15] + redf[(3 * 8 + ct) * 16 + l15];
            ws[KP_OFF + (size_t)blk * CC + ct * 16 + l15] = s;
        }
    }
}

// ---------------------------------------------------------------------------
// Kernel 2 (R9, validated): fused reduce + M-build, float4-vectorized.
// ---------------------------------------------------------------------------
__global__ __launch_bounds__(256) void mchain_kernel(const float* __restrict__ W,
                                                     const float* __restrict__ bias,
                                                     float* __restrict__ ws)
{
    __shared__ float4 W4s[CC * 32];    // W natural, float4-swizzled per row (64 KB)
    __shared__ float4 m0q[4][2][32];   // quarter partial sums (4 KB)
    __shared__ float m0row[2][CC];
    __shared__ float kpart[4];
    __shared__ float ksl[2];
    const int tid = threadIdx.x;
    const int b = blockIdx.y, x = blockIdx.x;
    const int c0 = x * 2;

    for (int idx = tid; idx < CC * 32; idx += 256) {
        int e = idx >> 5, d4 = idx & 31;
        W4s[(e << 5) + (d4 ^ (e & 31))] = ((const float4*)W)[idx];
    }

    // reduce 2 rows of M0 over 64 partials: 4-way quarter split, float4 loads
    {
        const int q  = tid >> 6;           // 0..3 partial quarter
        const int r  = (tid >> 5) & 1;     // row within pair
        const int c4 = tid & 31;           // float4 column
        const float4* pp = (const float4*)(ws + PP_OFF
                         + (size_t)(b * 64 + q * 16) * (CC * CC)
                         + (size_t)(c0 + r) * CC) + c4;
        float4 s0 = make_float4(0.f, 0.f, 0.f, 0.f);
#pragma unroll 4
        for (int p = 0; p < 16; p++) {
            float4 t = pp[(size_t)p * (CC * CC / 4)];
            s0.x += t.x; s0.y += t.y; s0.z += t.z; s0.w += t.w;
        }
        m0q[q][r][c4] = s0;
    }

    // reduce 2 Ksum entries over 64 partials
    {
        const int rr = tid >> 7, p = tid & 127;
        float v = 0.f;
        if (p < 64) v = ws[KP_OFF + (size_t)(b * 64 + p) * CC + c0 + rr];
#pragma unroll
        for (int off = 32; off > 0; off >>= 1) v += __shfl_xor(v, off, 64);
        if ((tid & 63) == 0) kpart[tid >> 6] = v;
    }
    __syncthreads();

    if (tid < 64) {
        const int r = tid >> 5, c4 = tid & 31;
        float4 a = m0q[0][r][c4], bq = m0q[1][r][c4];
        float4 c = m0q[2][r][c4], d = m0q[3][r][c4];
        float4 s;
        s.x = (a.x + bq.x) + (c.x + d.x);
        s.y = (a.y + bq.y) + (c.y + d.y);
        s.z = (a.z + bq.z) + (c.z + d.z);
        s.w = (a.w + bq.w) + (c.w + d.w);
        ((float4*)&m0row[r][0])[c4] = s;
    }
    if (tid < 2) {
        float s = kpart[tid * 2] + kpart[tid * 2 + 1];
        ksl[tid] = s;
        ws[KS_OFF + b * CC + c0 + tid] = s;
    }
    __syncthreads();

    // M = M0 @ W^T + Ksum b^T  (thread -> one output element)
    const int r = tid >> 7, e = tid & 127;
    const float4* mr = (const float4*)m0row[r];
    float m = 0.f;
#pragma unroll
    for (int d4 = 0; d4 < 32; d4++) {
        float4 a4 = mr[d4];                              // broadcast
        float4 w4 = W4s[(e << 5) + (d4 ^ (e & 31))];     // conflict-spread
        m += a4.x * w4.x + a4.y * w4.y + a4.z * w4.z + a4.w * w4.w;
    }
    m += ksl[r] * bias[e];
    ws[MM_OFF + (size_t)b * CC * CC + (size_t)(c0 + r) * CC + e] = m;
}

// ---------------------------------------------------------------------------
// Kernel 3 (R12, validated): split-bf16 MFMA numerator; exact fp32 denominator.
// ---------------------------------------------------------------------------
__global__ __launch_bounds__(512, 1) void out_kernel(const float* __restrict__ ws,
                                                     float* __restrict__ out)
{
    __shared__ __align__(16) unsigned short Msp[3 * CC * CC];  // 96 KB
    __shared__ float Ksl[CC];
    unsigned short* Mhi = Msp;
    unsigned short* Mmd = Msp + CC * CC;
    unsigned short* Mlo = Msp + 2 * CC * CC;

    const int tid = threadIdx.x;
    const int blk = blockIdx.x;     // 0..255
    const int b  = blk >> 6;
    const int r0 = (blk & 63) * 64;
    const float* M = ws + MM_OFF + (size_t)b * CC * CC;

    for (int e = tid; e < CC * CC; e += 512) {
        int k = e >> 7, col = e & 127;
        float mv = M[e];
        unsigned short hi = f2bf(mv);
        float r1 = mv - bf2f(hi);
        unsigned short md = f2bf(r1);
        unsigned short lo = f2bf(r1 - bf2f(md));
        int idx = (col << 7) + ((((k >> 3) ^ (col & 7)) << 3) | (k & 7));
        Mhi[idx] = hi; Mmd[idx] = md; Mlo[idx] = lo;
    }
    if (tid < CC) Ksl[tid] = ws[KS_OFF + b * CC + tid];

    const int w    = tid >> 6;        // wave 0..7
    const int lane = tid & 63;
    const int l15  = lane & 15;
    const int lg   = lane >> 4;
    const int rt   = w & 3;           // row-tile (4 x 16 = 64 rows)
    const int ch   = w >> 2;          // col-half (0: cols 0-63, 1: 64-127)

    const int arow = r0 + rt * 16 + l15;
    const float* Xr = ws + QP_OFF + ((size_t)b * NN + arow) * CC;

    f32x4 acc[4];
#pragma unroll
    for (int ct = 0; ct < 4; ct++) acc[ct] = (f32x4){0.f, 0.f, 0.f, 0.f};
    float sp = 0.f;

    __syncthreads();   // M + Ksum staged

#pragma unroll
    for (int ks = 0; ks < 4; ks++) {
        const int k0 = ks * 32 + lg * 8;
        float4 xa = *(const float4*)(Xr + k0);
        float4 xb = *(const float4*)(Xr + k0 + 4);
        float xs[8] = {xa.x, xa.y, xa.z, xa.w, xb.x, xb.y, xb.z, xb.w};
        short8 Ahi, Amd, Alo;
#pragma unroll
        for (int j = 0; j < 8; j++) {
            unsigned short h = f2bf(xs[j]);
            float r1 = xs[j] - bf2f(h);
            unsigned short m = f2bf(r1);
            Ahi[j] = (short)h;
            Amd[j] = (short)m;
            Alo[j] = (short)f2bf(r1 - bf2f(m));
            sp += xs[j] * Ksl[k0 + j];          // exact fp32 denominator
        }
        const int slot = ks * 4 + lg;
#pragma unroll
        for (int ct = 0; ct < 4; ct++) {
            int col  = ch * 64 + ct * 16 + l15;
            int fidx = (col << 7) + ((slot ^ (col & 7)) << 3);
            short8 Bhi = *(const short8*)(Mhi + fidx);
            short8 Bmd = *(const short8*)(Mmd + fidx);
            short8 Blo = *(const short8*)(Mlo + fidx);
            acc[ct] = __builtin_amdgcn_mfma_f32_16x16x32_bf16(Ahi, Bhi, acc[ct], 0, 0, 0);
            acc[ct] = __builtin_amdgcn_mfma_f32_16x16x32_bf16(Ahi, Bmd, acc[ct], 0, 0, 0);
            acc[ct] = __builtin_amdgcn_mfma_f32_16x16x32_bf16(Amd, Bhi, acc[ct], 0, 0, 0);
            acc[ct] = __builtin_amdgcn_mfma_f32_16x16x32_bf16(Ahi, Blo, acc[ct], 0, 0, 0);
            acc[ct] = __builtin_amdgcn_mfma_f32_16x16x32_bf16(Amd, Bmd, acc[ct], 0, 0, 0);
            acc[ct] = __builtin_amdgcn_mfma_f32_16x16x32_bf16(Alo, Bhi, acc[ct], 0, 0, 0);
        }
    }

    // reduce denominator over the 4 k-group lanes sharing l15
    sp += __shfl_xor(sp, 16, 64);
    sp += __shfl_xor(sp, 32, 64);

    // C/D layout: col = lane&15, row = lg*4 + r. Fetch s for the C-row.
#pragma unroll
    for (int r = 0; r < 4; r++) {
        const int rowt = lg * 4 + r;                 // row within 16-tile
        float srow = __shfl(sp, rowt, 64);           // lanes 0..15 hold rows 0..15
        const int gr = r0 + rt * 16 + rowt;
        float qn = ws[QN_OFF + (size_t)b * NN + gr];
        float inv = 1.0f / (srow + 1e-8f * qn);
        float* op = out + ((size_t)b * NN + gr) * CC + ch * 64;
#pragma unroll
        for (int ct = 0; ct < 4; ct++)
            op[ct * 16 + l15] = acc[ct][r] * inv;
    }
}

// ---------------------------------------------------------------------------
extern "C" void kernel_launch(void* const* d_in, const int* in_sizes, int n_in,
                              void* d_out, int out_size, void* d_ws, size_t ws_size,
                              hipStream_t stream)
{
    const float* q_node = (const float*)d_in[0];
    const float* k_node = (const float*)d_in[1];
    const float* v_node = (const float*)d_in[2];
    const float* W      = (const float*)d_in[3];
    const float* bias   = (const float*)d_in[4];
    float* out = (float*)d_out;
    float* ws  = (float*)d_ws;

    projpb_kernel<<<256, 512, 0, stream>>>(q_node, k_node, v_node, W, bias, ws);
    mchain_kernel<<<dim3(64, BB), 256, 0, stream>>>(W, bias, ws);
    out_kernel<<<256, 512, 0, stream>>>(ws, out);
}

// Round 14
// 118.607 us; speedup vs baseline: 1.0282x; 1.0249x over previous
//
#include <hip/hip_runtime.h>

#define BB 4
#define NN 4096
#define CC 128
#define NROWS (BB * NN)   // 16384 rows per tensor

// workspace layout (float offsets)
#define QN_OFF  0                              // |q_proj| per row (16384)
#define QP_OFF  (QN_OFF + NROWS)               // projected q, 16384 x 128
#define MM_OFF  (QP_OFF + NROWS * CC)          // B x 128 x 128  M = M0 W^T + Ksum b^T
#define KS_OFF  (MM_OFF + BB * CC * CC)        // B x 128  Ksum (sum of khat rows)
#define PP_OFF  (KS_OFF + BB * CC)             // 256 x 128 x 64 packed-bf16 partial M0s
#define KP_OFF  (PP_OFF + 256 * CC * 64)       // 256 x 128 partial ksums (fp32, exact)

typedef __attribute__((ext_vector_type(8))) short short8;
typedef __attribute__((ext_vector_type(4))) float f32x4;

__device__ __forceinline__ unsigned short f2bf(float f)
{
    union { float f; unsigned u; } v; v.f = f;
    unsigned r = (v.u + 0x7fffu + ((v.u >> 16) & 1u)) >> 16;   // RNE
    return (unsigned short)r;
}
__device__ __forceinline__ float bf2f(unsigned short h)
{
    union { unsigned u; float f; } v; v.u = ((unsigned)h) << 16;
    return v.f;
}

// ---------------------------------------------------------------------------
// Kernel 1 (R13 + packed-bf16 PP): fused projection (3-way-split bf16 MFMA)
// + partial-M build (6-term split-bf16 MFMA). 256 blocks x 512 threads.
// PP partials now stored as packed bf16 pairs (numerator-only path; error
// contribution to out <= ~1 absolute vs threshold 134). Halves PP traffic.
// ---------------------------------------------------------------------------
__global__ __launch_bounds__(512, 1) void projpb_kernel(
    const float* __restrict__ q_node, const float* __restrict__ k_node,
    const float* __restrict__ v_node, const float* __restrict__ W,
    const float* __restrict__ bias, float* __restrict__ ws)
{
    __shared__ __align__(16) unsigned short Wsp[3 * CC * CC];  // 96 KB
    __shared__ float redf[512];                                 // 2 KB
    unsigned short* Whi = Wsp;                 // [col][swizzled k] 128x128
    unsigned short* Wmd = Wsp + CC * CC;
    unsigned short* Wlo = Wsp + 2 * CC * CC;

    const int tid = threadIdx.x;

    // stage W as 3-way split bf16. B[k][c] = W[colbase+c][k] (out = X W^T).
    for (int e = tid; e < CC * CC; e += 512) {
        int col = e >> 7, k = e & 127;
        float wv = W[e];
        unsigned short hi = f2bf(wv);
        float r1 = wv - bf2f(hi);
        unsigned short md = f2bf(r1);
        unsigned short lo = f2bf(r1 - bf2f(md));
        int idx = (col << 7) + ((((k >> 3) ^ (col & 7)) << 3) | (k & 7));
        Whi[idx] = hi; Wmd[idx] = md; Wlo[idx] = lo;
    }

    const int blk  = blockIdx.x;      // 0..255
    const int base = blk * 64;
    const int w    = tid >> 6;        // wave 0..7
    const int lane = tid & 63;
    const int l15  = lane & 15;       // A-row / B-col / C-col within tile
    const int lg   = lane >> 4;       // k-group 0..3
    const bool isq = (w < 4);
    const int rt   = w & 3;           // row-tile within its tensor
    const float* X = isq ? q_node : k_node;
    const int arow = base + rt * 16 + l15;   // this lane's A row (global)

    f32x4 acc[8];
#pragma unroll
    for (int ct = 0; ct < 8; ct++) {
        float b = bias[ct * 16 + l15];
        acc[ct] = (f32x4){b, b, b, b};
    }

    __syncthreads();   // W staged

    const float* Xr = X + (size_t)arow * CC;
#pragma unroll
    for (int ks = 0; ks < 4; ks++) {
        const int k0 = ks * 32 + lg * 8;
        float4 xa = *(const float4*)(Xr + k0);
        float4 xb = *(const float4*)(Xr + k0 + 4);
        float xs[8] = {xa.x, xa.y, xa.z, xa.w, xb.x, xb.y, xb.z, xb.w};
        short8 Ahi, Amd, Alo;
#pragma unroll
        for (int j = 0; j < 8; j++) {
            unsigned short h = f2bf(xs[j]);
            float r1 = xs[j] - bf2f(h);
            unsigned short m = f2bf(r1);
            Ahi[j] = (short)h;
            Amd[j] = (short)m;
            Alo[j] = (short)f2bf(r1 - bf2f(m));
        }
        const int slot = ks * 4 + lg;      // k0 >> 3
#pragma unroll
        for (int ct = 0; ct < 8; ct++) {
            int col  = ct * 16 + l15;
            int fidx = (col << 7) + ((slot ^ (col & 7)) << 3);
            short8 Bhi = *(const short8*)(Whi + fidx);
            short8 Bmd = *(const short8*)(Wmd + fidx);
            short8 Blo = *(const short8*)(Wlo + fidx);
            acc[ct] = __builtin_amdgcn_mfma_f32_16x16x32_bf16(Ahi, Bhi, acc[ct], 0, 0, 0);
            acc[ct] = __builtin_amdgcn_mfma_f32_16x16x32_bf16(Ahi, Bmd, acc[ct], 0, 0, 0);
            acc[ct] = __builtin_amdgcn_mfma_f32_16x16x32_bf16(Amd, Bhi, acc[ct], 0, 0, 0);
            acc[ct] = __builtin_amdgcn_mfma_f32_16x16x32_bf16(Ahi, Blo, acc[ct], 0, 0, 0);
            acc[ct] = __builtin_amdgcn_mfma_f32_16x16x32_bf16(Amd, Bmd, acc[ct], 0, 0, 0);
            acc[ct] = __builtin_amdgcn_mfma_f32_16x16x32_bf16(Alo, Bhi, acc[ct], 0, 0, 0);
        }
    }

    // C/D layout (HW-verified): col = lane&15, row = (lane>>4)*4 + reg.
    float ss[4];
#pragma unroll
    for (int r = 0; r < 4; r++) {
        float t = 0.f;
#pragma unroll
        for (int ct = 0; ct < 8; ct++) t += acc[ct][r] * acc[ct][r];
#pragma unroll
        for (int off = 8; off > 0; off >>= 1) t += __shfl_xor(t, off, 16);
        ss[r] = t;
    }

    if (isq) {
#pragma unroll
        for (int r = 0; r < 4; r++) {
            int gr = base + rt * 16 + lg * 4 + r;
            float* qp = ws + QP_OFF + (size_t)gr * CC;
#pragma unroll
            for (int ct = 0; ct < 8; ct++) qp[ct * 16 + l15] = acc[ct][r];
            if (l15 == 0) ws[QN_OFF + gr] = sqrtf(ss[r]);
        }
    }

    __syncthreads();   // all waves done reading W LDS before overwrite

    // -------- phase 2: rank-64 partial M0 via split-bf16 MFMA --------
    unsigned short* Ahi_p = Wsp;               // 6 planes x 8192 shorts
    unsigned short* Amd_p = Wsp + 8192;
    unsigned short* Alo_p = Wsp + 16384;
    unsigned short* Bhi_p = Wsp + 24576;
    unsigned short* Bmd_p = Wsp + 32768;
    unsigned short* Blo_p = Wsp + 40960;

    // k-waves: normalize khat from registers -> A-planes + exact ksum partials
    if (!isq) {
        float ksp[8] = {0.f, 0.f, 0.f, 0.f, 0.f, 0.f, 0.f, 0.f};
#pragma unroll
        for (int r = 0; r < 4; r++) {
            float inv = 1.0f / sqrtf(ss[r]);
            int n = rt * 16 + lg * 4 + r;       // local n 0..63
#pragma unroll
            for (int ct = 0; ct < 8; ct++) {
                int c = ct * 16 + l15;
                float val = acc[ct][r] * inv;
                unsigned short h = f2bf(val);
                float r1 = val - bf2f(h);
                unsigned short m = f2bf(r1);
                unsigned short l = f2bf(r1 - bf2f(m));
                int idx = (c << 6) + ((((n >> 3) ^ (c & 7)) << 3) | (n & 7));
                Ahi_p[idx] = h; Amd_p[idx] = m; Alo_p[idx] = l;
                ksp[ct] += val;
            }
        }
#pragma unroll
        for (int ct = 0; ct < 8; ct++) {
            ksp[ct] += __shfl_xor(ksp[ct], 16, 64);
            ksp[ct] += __shfl_xor(ksp[ct], 32, 64);
            if (lg == 0) redf[(rt * 8 + ct) * 16 + l15] = ksp[ct];
        }
    }

    // all threads: stage v -> B-planes
    {
        const int c4v = tid & 31, nrv = (tid >> 5) & 15;
        const float* Vp = v_node + (size_t)base * CC;
#pragma unroll
        for (int i = 0; i < 4; i++) {
            int n = nrv + i * 16;
#pragma unroll
            for (int j = 0; j < 4; j++) {
                int d = c4v + 32 * j;
                float val = Vp[(size_t)n * CC + d];
                unsigned short h = f2bf(val);
                float r1 = val - bf2f(h);
                unsigned short m = f2bf(r1);
                unsigned short l = f2bf(r1 - bf2f(m));
                int idx = (d << 6) + ((((n >> 3) ^ (d & 7)) << 3) | (n & 7));
                Bhi_p[idx] = h; Bmd_p[idx] = m; Blo_p[idx] = l;
            }
        }
    }
    __syncthreads();

    // MFMA: wave w -> c-tile w (16 c rows) x all 128 d, K = 64 (2 steps)
    {
        f32x4 macc[8];
#pragma unroll
        for (int dt = 0; dt < 8; dt++) macc[dt] = (f32x4){0.f, 0.f, 0.f, 0.f};
        const int crow = w * 16 + l15;
#pragma unroll
        for (int ks2 = 0; ks2 < 2; ks2++) {
            const int slot = ks2 * 4 + lg;
            int aidx = (crow << 6) + ((slot ^ (crow & 7)) << 3);
            short8 Ah = *(const short8*)(Ahi_p + aidx);
            short8 Am = *(const short8*)(Amd_p + aidx);
            short8 Al = *(const short8*)(Alo_p + aidx);
#pragma unroll
            for (int dt = 0; dt < 8; dt++) {
                int d = dt * 16 + l15;
                int bidx = (d << 6) + ((slot ^ (d & 7)) << 3);
                short8 Bh = *(const short8*)(Bhi_p + bidx);
                short8 Bm = *(const short8*)(Bmd_p + bidx);
                short8 Bl = *(const short8*)(Blo_p + bidx);
                macc[dt] = __builtin_amdgcn_mfma_f32_16x16x32_bf16(Ah, Bh, macc[dt], 0, 0, 0);
                macc[dt] = __builtin_amdgcn_mfma_f32_16x16x32_bf16(Ah, Bm, macc[dt], 0, 0, 0);
                macc[dt] = __builtin_amdgcn_mfma_f32_16x16x32_bf16(Am, Bh, macc[dt], 0, 0, 0);
                macc[dt] = __builtin_amdgcn_mfma_f32_16x16x32_bf16(Ah, Bl, macc[dt], 0, 0, 0);
                macc[dt] = __builtin_amdgcn_mfma_f32_16x16x32_bf16(Am, Bm, macc[dt], 0, 0, 0);
                macc[dt] = __builtin_amdgcn_mfma_f32_16x16x32_bf16(Al, Bh, macc[dt], 0, 0, 0);
            }
        }

        // write packed-bf16 partial M0: word s*16 + l15 of row c holds
        // (bf16(M0[c][2s*16+l15]), bf16(M0[c][(2s+1)*16+l15])).
        unsigned* pp = (unsigned*)(ws + PP_OFF) + (size_t)blk * (CC * 64);
#pragma unroll
        for (int s = 0; s < 4; s++)
#pragma unroll
            for (int r = 0; r < 4; r++) {
                unsigned lo = f2bf(macc[2 * s][r]);
                unsigned hi = f2bf(macc[2 * s + 1][r]);
                pp[(size_t)(w * 16 + lg * 4 + r) * 64 + s * 16 + l15]
                    = lo | (hi << 16);
            }
    }

    // finalize ksum partial (exact fp32): lanes 0..15 of wave 0
    if (w == 0 && lg == 0) {
#pragma unroll
        for (int ct = 0; ct < 8; ct++) {
            float s = redf[(0 * 8 + ct) * 16 + l15] + redf[(1 * 8 + ct) * 16 + l15]
                    + redf[(2 * 8 + ct) * 16 + l15] + redf[(3 * 8 + ct) * 16 + l15];
            ws[KP_OFF + (size_t)blk * CC + ct * 16 + l15] = s;
        }
    }
}

// ---------------------------------------------------------------------------
// Kernel 2: fused reduce + M-build. M0 reduce now unpacks packed-bf16 PP
// (uint2 loads, 256 B contiguous per 32-thread group). Ksum + M exact fp32.
// ---------------------------------------------------------------------------
__global__ __launch_bounds__(256) void mchain_kernel(const float* __restrict__ W,
                                                     const float* __restrict__ bias,
                                                     float* __restrict__ ws)
{
    __shared__ float4 W4s[CC * 32];    // W natural, float4-swizzled per row (64 KB)
    __shared__ float m0q[4][2][CC];    // quarter partial sums (4 KB)
    __shared__ float m0row[2][CC];
    __shared__ float kpart[4];
    __shared__ float ksl[2];
    const int tid = threadIdx.x;
    const int b = blockIdx.y, x = blockIdx.x;
    const int c0 = x * 2;

    for (int idx = tid; idx < CC * 32; idx += 256) {
        int e = idx >> 5, d4 = idx & 31;
        W4s[(e << 5) + (d4 ^ (e & 31))] = ((const float4*)W)[idx];
    }

    // reduce 2 rows of M0 over 64 partials: 4-way quarter split, uint2 loads
    {
        const int q = tid >> 6, r = (tid >> 5) & 1, w32 = tid & 31;
        const unsigned* pp = (const unsigned*)(ws + PP_OFF)
            + ((size_t)(b * 64 + q * 16) * CC + (c0 + r)) * 64 + w32 * 2;
        float s0 = 0.f, s1 = 0.f, s2 = 0.f, s3 = 0.f;
#pragma unroll 4
        for (int p = 0; p < 16; p++) {
            uint2 t = *(const uint2*)(pp + (size_t)p * (CC * 64));
            s0 += bf2f((unsigned short)(t.x & 0xffffu));
            s1 += bf2f((unsigned short)(t.x >> 16));
            s2 += bf2f((unsigned short)(t.y & 0xffffu));
            s3 += bf2f((unsigned short)(t.y >> 16));
        }
        // word widx = s*16 + t  ->  d_lo = 32s + t, d_hi = 32s + 16 + t
        int w0 = w32 * 2, w1 = w32 * 2 + 1;
        int sA = w0 >> 4, tA = w0 & 15;
        int sB = w1 >> 4, tB = w1 & 15;
        m0q[q][r][32 * sA + tA]      = s0;
        m0q[q][r][32 * sA + 16 + tA] = s1;
        m0q[q][r][32 * sB + tB]      = s2;
        m0q[q][r][32 * sB + 16 + tB] = s3;
    }

    // reduce 2 Ksum entries over 64 partials (exact fp32)
    {
        const int rr = tid >> 7, p = tid & 127;
        float v = 0.f;
        if (p < 64) v = ws[KP_OFF + (size_t)(b * 64 + p) * CC + c0 + rr];
#pragma unroll
        for (int off = 32; off > 0; off >>= 1) v += __shfl_xor(v, off, 64);
        if ((tid & 63) == 0) kpart[tid >> 6] = v;
    }
    __syncthreads();

    // combine quarters
    {
        const int r = tid >> 7, d = tid & 127;
        m0row[r][d] = (m0q[0][r][d] + m0q[1][r][d])
                    + (m0q[2][r][d] + m0q[3][r][d]);
    }
    if (tid < 2) {
        float s = kpart[tid * 2] + kpart[tid * 2 + 1];
        ksl[tid] = s;
        ws[KS_OFF + b * CC + c0 + tid] = s;
    }
    __syncthreads();

    // M = M0 @ W^T + Ksum b^T  (thread -> one output element)
    const int r = tid >> 7, e = tid & 127;
    const float4* mr = (const float4*)m0row[r];
    float m = 0.f;
#pragma unroll
    for (int d4 = 0; d4 < 32; d4++) {
        float4 a4 = mr[d4];                              // broadcast
        float4 w4 = W4s[(e << 5) + (d4 ^ (e & 31))];     // conflict-spread
        m += a4.x * w4.x + a4.y * w4.y + a4.z * w4.z + a4.w * w4.w;
    }
    m += ksl[r] * bias[e];
    ws[MM_OFF + (size_t)b * CC * CC + (size_t)(c0 + r) * CC + e] = m;
}

// ---------------------------------------------------------------------------
// Kernel 3 (R12, validated): split-bf16 MFMA numerator; exact fp32 denominator.
// ---------------------------------------------------------------------------
__global__ __launch_bounds__(512, 1) void out_kernel(const float* __restrict__ ws,
                                                     float* __restrict__ out)
{
    __shared__ __align__(16) unsigned short Msp[3 * CC * CC];  // 96 KB
    __shared__ float Ksl[CC];
    unsigned short* Mhi = Msp;
    unsigned short* Mmd = Msp + CC * CC;
    unsigned short* Mlo = Msp + 2 * CC * CC;

    const int tid = threadIdx.x;
    const int blk = blockIdx.x;     // 0..255
    const int b  = blk >> 6;
    const int r0 = (blk & 63) * 64;
    const float* M = ws + MM_OFF + (size_t)b * CC * CC;

    for (int e = tid; e < CC * CC; e += 512) {
        int k = e >> 7, col = e & 127;
        float mv = M[e];
        unsigned short hi = f2bf(mv);
        float r1 = mv - bf2f(hi);
        unsigned short md = f2bf(r1);
        unsigned short lo = f2bf(r1 - bf2f(md));
        int idx = (col << 7) + ((((k >> 3) ^ (col & 7)) << 3) | (k & 7));
        Mhi[idx] = hi; Mmd[idx] = md; Mlo[idx] = lo;
    }
    if (tid < CC) Ksl[tid] = ws[KS_OFF + b * CC + tid];

    const int w    = tid >> 6;        // wave 0..7
    const int lane = tid & 63;
    const int l15  = lane & 15;
    const int lg   = lane >> 4;
    const int rt   = w & 3;           // row-tile (4 x 16 = 64 rows)
    const int ch   = w >> 2;          // col-half (0: cols 0-63, 1: 64-127)

    const int arow = r0 + rt * 16 + l15;
    const float* Xr = ws + QP_OFF + ((size_t)b * NN + arow) * CC;

    f32x4 acc[4];
#pragma unroll
    for (int ct = 0; ct < 4; ct++) acc[ct] = (f32x4){0.f, 0.f, 0.f, 0.f};
    float sp = 0.f;

    __syncthreads();   // M + Ksum staged

#pragma unroll
    for (int ks = 0; ks < 4; ks++) {
        const int k0 = ks * 32 + lg * 8;
        float4 xa = *(const float4*)(Xr + k0);
        float4 xb = *(const float4*)(Xr + k0 + 4);
        float xs[8] = {xa.x, xa.y, xa.z, xa.w, xb.x, xb.y, xb.z, xb.w};
        short8 Ahi, Amd, Alo;
#pragma unroll
        for (int j = 0; j < 8; j++) {
            unsigned short h = f2bf(xs[j]);
            float r1 = xs[j] - bf2f(h);
            unsigned short m = f2bf(r1);
            Ahi[j] = (short)h;
            Amd[j] = (short)m;
            Alo[j] = (short)f2bf(r1 - bf2f(m));
            sp += xs[j] * Ksl[k0 + j];          // exact fp32 denominator
        }
        const int slot = ks * 4 + lg;
#pragma unroll
        for (int ct = 0; ct < 4; ct++) {
            int col  = ch * 64 + ct * 16 + l15;
            int fidx = (col << 7) + ((slot ^ (col & 7)) << 3);
            short8 Bhi = *(const short8*)(Mhi + fidx);
            short8 Bmd = *(const short8*)(Mmd + fidx);
            short8 Blo = *(const short8*)(Mlo + fidx);
            acc[ct] = __builtin_amdgcn_mfma_f32_16x16x32_bf16(Ahi, Bhi, acc[ct], 0, 0, 0);
            acc[ct] = __builtin_amdgcn_mfma_f32_16x16x32_bf16(Ahi, Bmd, acc[ct], 0, 0, 0);
            acc[ct] = __builtin_amdgcn_mfma_f32_16x16x32_bf16(Amd, Bhi, acc[ct], 0, 0, 0);
            acc[ct] = __builtin_amdgcn_mfma_f32_16x16x32_bf16(Ahi, Blo, acc[ct], 0, 0, 0);
            acc[ct] = __builtin_amdgcn_mfma_f32_16x16x32_bf16(Amd, Bmd, acc[ct], 0, 0, 0);
            acc[ct] = __builtin_amdgcn_mfma_f32_16x16x32_bf16(Alo, Bhi, acc[ct], 0, 0, 0);
        }
    }

    // reduce denominator over the 4 k-group lanes sharing l15
    sp += __shfl_xor(sp, 16, 64);
    sp += __shfl_xor(sp, 32, 64);

    // C/D layout: col = lane&15, row = lg*4 + r. Fetch s for the C-row.
#pragma unroll
    for (int r = 0; r < 4; r++) {
        const int rowt = lg * 4 + r;                 // row within 16-tile
        float srow = __shfl(sp, rowt, 64);           // lanes 0..15 hold rows 0..15
        const int gr = r0 + rt * 16 + rowt;
        float qn = ws[QN_OFF + (size_t)b * NN + gr];
        float inv = 1.0f / (srow + 1e-8f * qn);
        float* op = out + ((size_t)b * NN + gr) * CC + ch * 64;
#pragma unroll
        for (int ct = 0; ct < 4; ct++)
            op[ct * 16 + l15] = acc[ct][r] * inv;
    }
}

// ---------------------------------------------------------------------------
extern "C" void kernel_launch(void* const* d_in, const int* in_sizes, int n_in,
                              void* d_out, int out_size, void* d_ws, size_t ws_size,
                              hipStream_t stream)
{
    const float* q_node = (const float*)d_in[0];
    const float* k_node = (const float*)d_in[1];
    const float* v_node = (const float*)d_in[2];
    const float* W      = (const float*)d_in[3];
    const float* bias   = (const float*)d_in[4];
    float* out = (float*)d_out;
    float* ws  = (float*)d_ws;

    projpb_kernel<<<256, 512, 0, stream>>>(q_node, k_node, v_node, W, bias, ws);
    mchain_kernel<<<dim3(64, BB), 256, 0, stream>>>(W, bias, ws);
    out_kernel<<<256, 512, 0, stream>>>(ws, out);
}

// Round 15
// 113.992 us; speedup vs baseline: 1.0698x; 1.0405x over previous
//
#include <hip/hip_runtime.h>

#define BB 4
#define NN 4096
#define CC 128
#define NROWS (BB * NN)   // 16384 rows per tensor

// workspace layout (float offsets)
#define QN_OFF  0                              // |q_proj| per row (16384)
#define QP_OFF  (QN_OFF + NROWS)               // projected q, 16384 x 128
#define MM_OFF  (QP_OFF + NROWS * CC)          // B x 128 x 128  M = M0 W^T + Ksum b^T
#define KS_OFF  (MM_OFF + BB * CC * CC)        // B x 128  Ksum (sum of khat rows)
#define PP_OFF  (KS_OFF + BB * CC)             // 256 x 128 x 64 packed-bf16 partial M0s
#define KP_OFF  (PP_OFF + 256 * CC * 64)       // 256 x 128 partial ksums (fp32, exact)

typedef __attribute__((ext_vector_type(8))) short short8;
typedef __attribute__((ext_vector_type(4))) float f32x4;

__device__ __forceinline__ unsigned short f2bf(float f)
{
    union { float f; unsigned u; } v; v.f = f;
    unsigned r = (v.u + 0x7fffu + ((v.u >> 16) & 1u)) >> 16;   // RNE
    return (unsigned short)r;
}
__device__ __forceinline__ float bf2f(unsigned short h)
{
    union { unsigned u; float f; } v; v.u = ((unsigned)h) << 16;
    return v.f;
}

// ---------------------------------------------------------------------------
// Kernel 1: fused projection (6-term split-bf16 MFMA, denominator-grade
// precision ~2^-27) + partial-M build (NEW: 2-plane hi/md, 3-term MFMA —
// numerator-grade ~2^-16; R14 proved 2^-9 passes). 256 blocks x 512 threads.
// PP stored packed bf16 (validated R14).
// ---------------------------------------------------------------------------
__global__ __launch_bounds__(512, 1) void projpb_kernel(
    const float* __restrict__ q_node, const float* __restrict__ k_node,
    const float* __restrict__ v_node, const float* __restrict__ W,
    const float* __restrict__ bias, float* __restrict__ ws)
{
    __shared__ __align__(16) unsigned short Wsp[3 * CC * CC];  // 96 KB
    __shared__ float redf[512];                                 // 2 KB
    unsigned short* Whi = Wsp;                 // [col][swizzled k] 128x128
    unsigned short* Wmd = Wsp + CC * CC;
    unsigned short* Wlo = Wsp + 2 * CC * CC;

    const int tid = threadIdx.x;

    // stage W as 3-way split bf16. B[k][c] = W[colbase+c][k] (out = X W^T).
    for (int e = tid; e < CC * CC; e += 512) {
        int col = e >> 7, k = e & 127;
        float wv = W[e];
        unsigned short hi = f2bf(wv);
        float r1 = wv - bf2f(hi);
        unsigned short md = f2bf(r1);
        unsigned short lo = f2bf(r1 - bf2f(md));
        int idx = (col << 7) + ((((k >> 3) ^ (col & 7)) << 3) | (k & 7));
        Whi[idx] = hi; Wmd[idx] = md; Wlo[idx] = lo;
    }

    const int blk  = blockIdx.x;      // 0..255
    const int base = blk * 64;
    const int w    = tid >> 6;        // wave 0..7
    const int lane = tid & 63;
    const int l15  = lane & 15;       // A-row / B-col / C-col within tile
    const int lg   = lane >> 4;       // k-group 0..3
    const bool isq = (w < 4);
    const int rt   = w & 3;           // row-tile within its tensor
    const float* X = isq ? q_node : k_node;
    const int arow = base + rt * 16 + l15;   // this lane's A row (global)

    f32x4 acc[8];
#pragma unroll
    for (int ct = 0; ct < 8; ct++) {
        float b = bias[ct * 16 + l15];
        acc[ct] = (f32x4){b, b, b, b};
    }

    __syncthreads();   // W staged

    const float* Xr = X + (size_t)arow * CC;
#pragma unroll
    for (int ks = 0; ks < 4; ks++) {
        const int k0 = ks * 32 + lg * 8;
        float4 xa = *(const float4*)(Xr + k0);
        float4 xb = *(const float4*)(Xr + k0 + 4);
        float xs[8] = {xa.x, xa.y, xa.z, xa.w, xb.x, xb.y, xb.z, xb.w};
        short8 Ahi, Amd, Alo;
#pragma unroll
        for (int j = 0; j < 8; j++) {
            unsigned short h = f2bf(xs[j]);
            float r1 = xs[j] - bf2f(h);
            unsigned short m = f2bf(r1);
            Ahi[j] = (short)h;
            Amd[j] = (short)m;
            Alo[j] = (short)f2bf(r1 - bf2f(m));
        }
        const int slot = ks * 4 + lg;      // k0 >> 3
#pragma unroll
        for (int ct = 0; ct < 8; ct++) {
            int col  = ct * 16 + l15;
            int fidx = (col << 7) + ((slot ^ (col & 7)) << 3);
            short8 Bhi = *(const short8*)(Whi + fidx);
            short8 Bmd = *(const short8*)(Wmd + fidx);
            short8 Blo = *(const short8*)(Wlo + fidx);
            acc[ct] = __builtin_amdgcn_mfma_f32_16x16x32_bf16(Ahi, Bhi, acc[ct], 0, 0, 0);
            acc[ct] = __builtin_amdgcn_mfma_f32_16x16x32_bf16(Ahi, Bmd, acc[ct], 0, 0, 0);
            acc[ct] = __builtin_amdgcn_mfma_f32_16x16x32_bf16(Amd, Bhi, acc[ct], 0, 0, 0);
            acc[ct] = __builtin_amdgcn_mfma_f32_16x16x32_bf16(Ahi, Blo, acc[ct], 0, 0, 0);
            acc[ct] = __builtin_amdgcn_mfma_f32_16x16x32_bf16(Amd, Bmd, acc[ct], 0, 0, 0);
            acc[ct] = __builtin_amdgcn_mfma_f32_16x16x32_bf16(Alo, Bhi, acc[ct], 0, 0, 0);
        }
    }

    // C/D layout (HW-verified): col = lane&15, row = (lane>>4)*4 + reg.
    float ss[4];
#pragma unroll
    for (int r = 0; r < 4; r++) {
        float t = 0.f;
#pragma unroll
        for (int ct = 0; ct < 8; ct++) t += acc[ct][r] * acc[ct][r];
#pragma unroll
        for (int off = 8; off > 0; off >>= 1) t += __shfl_xor(t, off, 16);
        ss[r] = t;
    }

    if (isq) {
#pragma unroll
        for (int r = 0; r < 4; r++) {
            int gr = base + rt * 16 + lg * 4 + r;
            float* qp = ws + QP_OFF + (size_t)gr * CC;
#pragma unroll
            for (int ct = 0; ct < 8; ct++) qp[ct * 16 + l15] = acc[ct][r];
            if (l15 == 0) ws[QN_OFF + gr] = sqrtf(ss[r]);
        }
    }

    __syncthreads();   // all waves done reading W LDS before overwrite

    // -------- phase 2: rank-64 partial M0, 2-plane hi/md 3-term MFMA ------
    unsigned short* Ahi_p = Wsp;               // 4 planes x 8192 shorts = 64 KB
    unsigned short* Amd_p = Wsp + 8192;
    unsigned short* Bhi_p = Wsp + 16384;
    unsigned short* Bmd_p = Wsp + 24576;

    // k-waves: normalize khat from registers -> A-planes + exact ksum partials
    if (!isq) {
        float ksp[8] = {0.f, 0.f, 0.f, 0.f, 0.f, 0.f, 0.f, 0.f};
#pragma unroll
        for (int r = 0; r < 4; r++) {
            float inv = 1.0f / sqrtf(ss[r]);
            int n = rt * 16 + lg * 4 + r;       // local n 0..63
#pragma unroll
            for (int ct = 0; ct < 8; ct++) {
                int c = ct * 16 + l15;
                float val = acc[ct][r] * inv;
                unsigned short h = f2bf(val);
                unsigned short m = f2bf(val - bf2f(h));
                int idx = (c << 6) + ((((n >> 3) ^ (c & 7)) << 3) | (n & 7));
                Ahi_p[idx] = h; Amd_p[idx] = m;
                ksp[ct] += val;
            }
        }
#pragma unroll
        for (int ct = 0; ct < 8; ct++) {
            ksp[ct] += __shfl_xor(ksp[ct], 16, 64);
            ksp[ct] += __shfl_xor(ksp[ct], 32, 64);
            if (lg == 0) redf[(rt * 8 + ct) * 16 + l15] = ksp[ct];
        }
    }

    // all threads: stage v -> B-planes (hi/md)
    {
        const int c4v = tid & 31, nrv = (tid >> 5) & 15;
        const float* Vp = v_node + (size_t)base * CC;
#pragma unroll
        for (int i = 0; i < 4; i++) {
            int n = nrv + i * 16;
#pragma unroll
            for (int j = 0; j < 4; j++) {
                int d = c4v + 32 * j;
                float val = Vp[(size_t)n * CC + d];
                unsigned short h = f2bf(val);
                unsigned short m = f2bf(val - bf2f(h));
                int idx = (d << 6) + ((((n >> 3) ^ (d & 7)) << 3) | (n & 7));
                Bhi_p[idx] = h; Bmd_p[idx] = m;
            }
        }
    }
    __syncthreads();

    // MFMA: wave w -> c-tile w (16 c rows) x all 128 d, K = 64 (2 steps)
    {
        f32x4 macc[8];
#pragma unroll
        for (int dt = 0; dt < 8; dt++) macc[dt] = (f32x4){0.f, 0.f, 0.f, 0.f};
        const int crow = w * 16 + l15;
#pragma unroll
        for (int ks2 = 0; ks2 < 2; ks2++) {
            const int slot = ks2 * 4 + lg;
            int aidx = (crow << 6) + ((slot ^ (crow & 7)) << 3);
            short8 Ah = *(const short8*)(Ahi_p + aidx);
            short8 Am = *(const short8*)(Amd_p + aidx);
#pragma unroll
            for (int dt = 0; dt < 8; dt++) {
                int d = dt * 16 + l15;
                int bidx = (d << 6) + ((slot ^ (d & 7)) << 3);
                short8 Bh = *(const short8*)(Bhi_p + bidx);
                short8 Bm = *(const short8*)(Bmd_p + bidx);
                macc[dt] = __builtin_amdgcn_mfma_f32_16x16x32_bf16(Ah, Bh, macc[dt], 0, 0, 0);
                macc[dt] = __builtin_amdgcn_mfma_f32_16x16x32_bf16(Ah, Bm, macc[dt], 0, 0, 0);
                macc[dt] = __builtin_amdgcn_mfma_f32_16x16x32_bf16(Am, Bh, macc[dt], 0, 0, 0);
            }
        }

        // write packed-bf16 partial M0 (validated R14)
        unsigned* pp = (unsigned*)(ws + PP_OFF) + (size_t)blk * (CC * 64);
#pragma unroll
        for (int s = 0; s < 4; s++)
#pragma unroll
            for (int r = 0; r < 4; r++) {
                unsigned lo = f2bf(macc[2 * s][r]);
                unsigned hi = f2bf(macc[2 * s + 1][r]);
                pp[(size_t)(w * 16 + lg * 4 + r) * 64 + s * 16 + l15]
                    = lo | (hi << 16);
            }
    }

    // finalize ksum partial (exact fp32): lanes 0..15 of wave 0
    if (w == 0 && lg == 0) {
#pragma unroll
        for (int ct = 0; ct < 8; ct++) {
            float s = redf[(0 * 8 + ct) * 16 + l15] + redf[(1 * 8 + ct) * 16 + l15]
                    + redf[(2 * 8 + ct) * 16 + l15] + redf[(3 * 8 + ct) * 16 + l15];
            ws[KP_OFF + (size_t)blk * CC + ct * 16 + l15] = s;
        }
    }
}

// ---------------------------------------------------------------------------
// Kernel 2 (R14, validated): fused reduce + M-build, packed-bf16 PP unpack.
// ---------------------------------------------------------------------------
__global__ __launch_bounds__(256) void mchain_kernel(const float* __restrict__ W,
                                                     const float* __restrict__ bias,
                                                     float* __restrict__ ws)
{
    __shared__ float4 W4s[CC * 32];    // W natural, float4-swizzled per row (64 KB)
    __shared__ float m0q[4][2][CC];    // quarter partial sums (4 KB)
    __shared__ float m0row[2][CC];
    __shared__ float kpart[4];
    __shared__ float ksl[2];
    const int tid = threadIdx.x;
    const int b = blockIdx.y, x = blockIdx.x;
    const int c0 = x * 2;

    for (int idx = tid; idx < CC * 32; idx += 256) {
        int e = idx >> 5, d4 = idx & 31;
        W4s[(e << 5) + (d4 ^ (e & 31))] = ((const float4*)W)[idx];
    }

    // reduce 2 rows of M0 over 64 partials: 4-way quarter split, uint2 loads
    {
        const int q = tid >> 6, r = (tid >> 5) & 1, w32 = tid & 31;
        const unsigned* pp = (const unsigned*)(ws + PP_OFF)
            + ((size_t)(b * 64 + q * 16) * CC + (c0 + r)) * 64 + w32 * 2;
        float s0 = 0.f, s1 = 0.f, s2 = 0.f, s3 = 0.f;
#pragma unroll 4
        for (int p = 0; p < 16; p++) {
            uint2 t = *(const uint2*)(pp + (size_t)p * (CC * 64));
            s0 += bf2f((unsigned short)(t.x & 0xffffu));
            s1 += bf2f((unsigned short)(t.x >> 16));
            s2 += bf2f((unsigned short)(t.y & 0xffffu));
            s3 += bf2f((unsigned short)(t.y >> 16));
        }
        // word widx = s*16 + t  ->  d_lo = 32s + t, d_hi = 32s + 16 + t
        int w0 = w32 * 2, w1 = w32 * 2 + 1;
        int sA = w0 >> 4, tA = w0 & 15;
        int sB = w1 >> 4, tB = w1 & 15;
        m0q[q][r][32 * sA + tA]      = s0;
        m0q[q][r][32 * sA + 16 + tA] = s1;
        m0q[q][r][32 * sB + tB]      = s2;
        m0q[q][r][32 * sB + 16 + tB] = s3;
    }

    // reduce 2 Ksum entries over 64 partials (exact fp32)
    {
        const int rr = tid >> 7, p = tid & 127;
        float v = 0.f;
        if (p < 64) v = ws[KP_OFF + (size_t)(b * 64 + p) * CC + c0 + rr];
#pragma unroll
        for (int off = 32; off > 0; off >>= 1) v += __shfl_xor(v, off, 64);
        if ((tid & 63) == 0) kpart[tid >> 6] = v;
    }
    __syncthreads();

    // combine quarters
    {
        const int r = tid >> 7, d = tid & 127;
        m0row[r][d] = (m0q[0][r][d] + m0q[1][r][d])
                    + (m0q[2][r][d] + m0q[3][r][d]);
    }
    if (tid < 2) {
        float s = kpart[tid * 2] + kpart[tid * 2 + 1];
        ksl[tid] = s;
        ws[KS_OFF + b * CC + c0 + tid] = s;
    }
    __syncthreads();

    // M = M0 @ W^T + Ksum b^T  (thread -> one output element)
    const int r = tid >> 7, e = tid & 127;
    const float4* mr = (const float4*)m0row[r];
    float m = 0.f;
#pragma unroll
    for (int d4 = 0; d4 < 32; d4++) {
        float4 a4 = mr[d4];                              // broadcast
        float4 w4 = W4s[(e << 5) + (d4 ^ (e & 31))];     // conflict-spread
        m += a4.x * w4.x + a4.y * w4.y + a4.z * w4.z + a4.w * w4.w;
    }
    m += ksl[r] * bias[e];
    ws[MM_OFF + (size_t)b * CC * CC + (size_t)(c0 + r) * CC + e] = m;
}

// ---------------------------------------------------------------------------
// Kernel 3: split-bf16 MFMA numerator, NEW 2-plane hi/md (3-term, ~2^-16);
// exact fp32 denominator. LDS 64.5 KB -> 2 blocks/CU (was 1).
// ---------------------------------------------------------------------------
__global__ __launch_bounds__(512, 4) void out_kernel(const float* __restrict__ ws,
                                                     float* __restrict__ out)
{
    __shared__ __align__(16) unsigned short Msp[2 * CC * CC];  // 64 KB
    __shared__ float Ksl[CC];
    unsigned short* Mhi = Msp;
    unsigned short* Mmd = Msp + CC * CC;

    const int tid = threadIdx.x;
    const int blk = blockIdx.x;     // 0..255
    const int b  = blk >> 6;
    const int r0 = (blk & 63) * 64;
    const float* M = ws + MM_OFF + (size_t)b * CC * CC;

    for (int e = tid; e < CC * CC; e += 512) {
        int k = e >> 7, col = e & 127;
        float mv = M[e];
        unsigned short hi = f2bf(mv);
        unsigned short md = f2bf(mv - bf2f(hi));
        int idx = (col << 7) + ((((k >> 3) ^ (col & 7)) << 3) | (k & 7));
        Mhi[idx] = hi; Mmd[idx] = md;
    }
    if (tid < CC) Ksl[tid] = ws[KS_OFF + b * CC + tid];

    const int w    = tid >> 6;        // wave 0..7
    const int lane = tid & 63;
    const int l15  = lane & 15;
    const int lg   = lane >> 4;
    const int rt   = w & 3;           // row-tile (4 x 16 = 64 rows)
    const int ch   = w >> 2;          // col-half (0: cols 0-63, 1: 64-127)

    const int arow = r0 + rt * 16 + l15;
    const float* Xr = ws + QP_OFF + ((size_t)b * NN + arow) * CC;

    f32x4 acc[4];
#pragma unroll
    for (int ct = 0; ct < 4; ct++) acc[ct] = (f32x4){0.f, 0.f, 0.f, 0.f};
    float sp = 0.f;

    __syncthreads();   // M + Ksum staged

#pragma unroll
    for (int ks = 0; ks < 4; ks++) {
        const int k0 = ks * 32 + lg * 8;
        float4 xa = *(const float4*)(Xr + k0);
        float4 xb = *(const float4*)(Xr + k0 + 4);
        float xs[8] = {xa.x, xa.y, xa.z, xa.w, xb.x, xb.y, xb.z, xb.w};
        short8 Ahi, Amd;
#pragma unroll
        for (int j = 0; j < 8; j++) {
            unsigned short h = f2bf(xs[j]);
            Ahi[j] = (short)h;
            Amd[j] = (short)f2bf(xs[j] - bf2f(h));
            sp += xs[j] * Ksl[k0 + j];          // exact fp32 denominator
        }
        const int slot = ks * 4 + lg;
#pragma unroll
        for (int ct = 0; ct < 4; ct++) {
            int col  = ch * 64 + ct * 16 + l15;
            int fidx = (col << 7) + ((slot ^ (col & 7)) << 3);
            short8 Bhi = *(const short8*)(Mhi + fidx);
            short8 Bmd = *(const short8*)(Mmd + fidx);
            acc[ct] = __builtin_amdgcn_mfma_f32_16x16x32_bf16(Ahi, Bhi, acc[ct], 0, 0, 0);
            acc[ct] = __builtin_amdgcn_mfma_f32_16x16x32_bf16(Ahi, Bmd, acc[ct], 0, 0, 0);
            acc[ct] = __builtin_amdgcn_mfma_f32_16x16x32_bf16(Amd, Bhi, acc[ct], 0, 0, 0);
        }
    }

    // reduce denominator over the 4 k-group lanes sharing l15
    sp += __shfl_xor(sp, 16, 64);
    sp += __shfl_xor(sp, 32, 64);

    // C/D layout: col = lane&15, row = lg*4 + r. Fetch s for the C-row.
#pragma unroll
    for (int r = 0; r < 4; r++) {
        const int rowt = lg * 4 + r;                 // row within 16-tile
        float srow = __shfl(sp, rowt, 64);           // lanes 0..15 hold rows 0..15
        const int gr = r0 + rt * 16 + rowt;
        float qn = ws[QN_OFF + (size_t)b * NN + gr];
        float inv = 1.0f / (srow + 1e-8f * qn);
        float* op = out + ((size_t)b * NN + gr) * CC + ch * 64;
#pragma unroll
        for (int ct = 0; ct < 4; ct++)
            op[ct * 16 + l15] = acc[ct][r] * inv;
    }
}

// ---------------------------------------------------------------------------
extern "C" void kernel_launch(void* const* d_in, const int* in_sizes, int n_in,
                              void* d_out, int out_size, void* d_ws, size_t ws_size,
                              hipStream_t stream)
{
    const float* q_node = (const float*)d_in[0];
    const float* k_node = (const float*)d_in[1];
    const float* v_node = (const float*)d_in[2];
    const float* W      = (const float*)d_in[3];
    const float* bias   = (const float*)d_in[4];
    float* out = (float*)d_out;
    float* ws  = (float*)d_ws;

    projpb_kernel<<<256, 512, 0, stream>>>(q_node, k_node, v_node, W, bias, ws);
    mchain_kernel<<<dim3(64, BB), 256, 0, stream>>>(W, bias, ws);
    out_kernel<<<256, 512, 0, stream>>>(ws, out);
}